// Round 1
// baseline (11655.801 us; speedup 1.0000x reference)
//
#include <hip/hip_runtime.h>

// Problem constants (from reference)
#define NN 100000          // total nodes
#define NE 3200000         // edges
#define NA 60000           // type-a nodes, d_a=256
#define NB 40000           // type-b nodes, d_b=128
#define NHID 256
#define NOUT 64

// ---------------------------------------------------------------------------
// Tiled fp32 GEMM: C[M,N] = op(A[M,K]) @ B[K,N] + bias[N], optional relu.
// 64x64 tile, BK=16, 256 threads, 4x4 accum per thread.
// Requires: N % 64 == 0, K % 16 == 0. M arbitrary (guarded).
// RELU_IN: apply relu to A elements on load. RELU_OUT: relu on store.
// ---------------------------------------------------------------------------
template <int RELU_IN, int RELU_OUT>
__global__ __launch_bounds__(256) void gemm_bias(
    const float* __restrict__ A, const float* __restrict__ B,
    const float* __restrict__ bias, float* __restrict__ C,
    int M, int N, int K) {
  __shared__ float As[16][64];  // As[k][m] (transposed store)
  __shared__ float Bs[16][64];  // Bs[k][n]

  const int tid = threadIdx.x;
  const int tx = tid & 15;        // 0..15 -> 4 cols each
  const int ty = tid >> 4;        // 0..15 -> 4 rows each
  const int bm = blockIdx.x * 64;
  const int bn = blockIdx.y * 64;

  float acc[4][4] = {};

  const int e = tid * 4;
  const int ar = e >> 4;   // A tile row   (0..63)
  const int ak = e & 15;   // A tile k     (0,4,8,12)
  const int bk = e >> 6;   // B tile k     (0..15)
  const int bn4 = e & 63;  // B tile n     (0,4,..,60)

  for (int k0 = 0; k0 < K; k0 += 16) {
    // --- load A tile (64 x 16), coalesced float4 along K ---
    {
      float4 v = make_float4(0.f, 0.f, 0.f, 0.f);
      const int grow = bm + ar;
      if (grow < M)
        v = *reinterpret_cast<const float4*>(&A[(size_t)grow * K + k0 + ak]);
      if (RELU_IN) {
        v.x = fmaxf(v.x, 0.f); v.y = fmaxf(v.y, 0.f);
        v.z = fmaxf(v.z, 0.f); v.w = fmaxf(v.w, 0.f);
      }
      As[ak + 0][ar] = v.x;
      As[ak + 1][ar] = v.y;
      As[ak + 2][ar] = v.z;
      As[ak + 3][ar] = v.w;
    }
    // --- load B tile (16 x 64), coalesced float4 along N ---
    {
      float4 v = *reinterpret_cast<const float4*>(
          &B[(size_t)(k0 + bk) * N + bn + bn4]);
      *reinterpret_cast<float4*>(&Bs[bk][bn4]) = v;
    }
    __syncthreads();

#pragma unroll
    for (int k = 0; k < 16; ++k) {
      float4 a = *reinterpret_cast<const float4*>(&As[k][ty * 4]);
      float4 b = *reinterpret_cast<const float4*>(&Bs[k][tx * 4]);
      const float av[4] = {a.x, a.y, a.z, a.w};
      const float bv[4] = {b.x, b.y, b.z, b.w};
#pragma unroll
      for (int i = 0; i < 4; ++i)
#pragma unroll
        for (int j = 0; j < 4; ++j) acc[i][j] += av[i] * bv[j];
    }
    __syncthreads();
  }

  // --- epilogue: bias (+relu), float4 stores ---
  const int cn = bn + tx * 4;
  float4 bv = *reinterpret_cast<const float4*>(&bias[cn]);
#pragma unroll
  for (int i = 0; i < 4; ++i) {
    const int row = bm + ty * 4 + i;
    if (row >= M) continue;
    float4 o;
    o.x = acc[i][0] + bv.x;
    o.y = acc[i][1] + bv.y;
    o.z = acc[i][2] + bv.z;
    o.w = acc[i][3] + bv.w;
    if (RELU_OUT) {
      o.x = fmaxf(o.x, 0.f); o.y = fmaxf(o.y, 0.f);
      o.z = fmaxf(o.z, 0.f); o.w = fmaxf(o.w, 0.f);
    }
    *reinterpret_cast<float4*>(&C[(size_t)row * N + cn]) = o;
  }
}

// ---------------------------------------------------------------------------
// COO SpMM, feature width 256: one wave per edge, lane handles 4 floats.
// Y[rows[e]] += vals[e] * X[cols[e]]  (atomic scatter)
// ---------------------------------------------------------------------------
__global__ __launch_bounds__(256) void spmm256_atomic(
    const int* __restrict__ rows, const int* __restrict__ cols,
    const float* __restrict__ vals, const float* __restrict__ X,
    float* __restrict__ Y, int nE) {
  const int wid = (int)((blockIdx.x * (size_t)blockDim.x + threadIdx.x) >> 6);
  const int lane = threadIdx.x & 63;
  if (wid >= nE) return;
  const int r = rows[wid];
  const int c = cols[wid];
  const float v = vals[wid];
  const float4 x =
      reinterpret_cast<const float4*>(X + (size_t)c * 256)[lane];
  float* y = Y + (size_t)r * 256 + lane * 4;
  atomicAdd(y + 0, v * x.x);
  atomicAdd(y + 1, v * x.y);
  atomicAdd(y + 2, v * x.z);
  atomicAdd(y + 3, v * x.w);
}

// ---------------------------------------------------------------------------
// COO SpMM, feature width 64: one wave per edge, lane handles 1 float.
// ---------------------------------------------------------------------------
__global__ __launch_bounds__(256) void spmm64_atomic(
    const int* __restrict__ rows, const int* __restrict__ cols,
    const float* __restrict__ vals, const float* __restrict__ X,
    float* __restrict__ Y, int nE) {
  const int wid = (int)((blockIdx.x * (size_t)blockDim.x + threadIdx.x) >> 6);
  const int lane = threadIdx.x & 63;
  if (wid >= nE) return;
  const int r = rows[wid];
  const int c = cols[wid];
  const float v = vals[wid];
  const float x = X[(size_t)c * 64 + lane];
  atomicAdd(Y + (size_t)r * 64 + lane, v * x);
}

extern "C" void kernel_launch(void* const* d_in, const int* in_sizes, int n_in,
                              void* d_out, int out_size, void* d_ws,
                              size_t ws_size, hipStream_t stream) {
  const float* x_a  = (const float*)d_in[0];   // [60000,256]
  const float* x_b  = (const float*)d_in[1];   // [40000,128]
  const int*   rows = (const int*)d_in[2];     // [NE]
  const int*   cols = (const int*)d_in[3];     // [NE]
  const float* vals = (const float*)d_in[4];   // [NE]
  const float* W1a  = (const float*)d_in[5];   // [256,256]
  const float* b1a  = (const float*)d_in[6];   // [256]
  const float* W1b  = (const float*)d_in[7];   // [128,256]
  const float* b1b  = (const float*)d_in[8];   // [256]
  const float* Wf   = (const float*)d_in[9];   // [256,256]
  const float* bf   = (const float*)d_in[10];  // [256]
  const float* W2   = (const float*)d_in[11];  // [256,64]
  const float* b2   = (const float*)d_in[12];  // [64]
  float* out = (float*)d_out;                  // [100000,64]

  const size_t hidBytes = (size_t)NN * NHID * sizeof(float);  // 102.4 MB
  float* h = (float*)d_ws;                         // [NN,256]
  float* z = (float*)((char*)d_ws + hidBytes);     // [NN,256]
  // s1 reuses h; z2 reuses z.

  // 1) h_a = relu(x_a @ W1a + b1a)
  gemm_bias<0, 1><<<dim3((NA + 63) / 64, NHID / 64), 256, 0, stream>>>(
      x_a, W1a, b1a, h, NA, NHID, 256);
  // 2) h_b = relu(x_b @ W1b + b1b)
  gemm_bias<0, 1><<<dim3((NB + 63) / 64, NHID / 64), 256, 0, stream>>>(
      x_b, W1b, b1b, h + (size_t)NA * NHID, NB, NHID, 128);
  // 3) z = h @ Wf + bf
  gemm_bias<0, 0><<<dim3((NN + 63) / 64, NHID / 64), 256, 0, stream>>>(
      h, Wf, bf, z, NN, NHID, NHID);
  // 4) s1 = spmm(z)   (s1 reuses h buffer; zero it first)
  hipMemsetAsync(h, 0, hidBytes, stream);
  spmm256_atomic<<<(NE + 3) / 4, 256, 0, stream>>>(rows, cols, vals, z, h, NE);
  // 5) z2 = relu(s1) @ W2 + b2   (into z buffer, fused relu on input)
  gemm_bias<1, 0><<<dim3((NN + 63) / 64, NOUT / 64), 256, 0, stream>>>(
      h, W2, b2, z, NN, NOUT, NHID);
  // 6) out = spmm(z2)
  hipMemsetAsync(out, 0, (size_t)NN * NOUT * sizeof(float), stream);
  spmm64_atomic<<<(NE + 3) / 4, 256, 0, stream>>>(rows, cols, vals, z, out, NE);
}

// Round 2
// 1290.735 us; speedup vs baseline: 9.0304x; 9.0304x over previous
//
#include <hip/hip_runtime.h>

#define NN 100000
#define NE 3200000
#define NA 60000
#define NB 40000
#define NHID 256
#define NOUT 64

typedef unsigned short u16;
typedef unsigned int u32;

__device__ inline float bf2f(u16 u) { return __uint_as_float(((u32)u) << 16); }
__device__ inline u16 f2bf(float f) {
  u32 u = __float_as_uint(f);
  u32 r = (u + 0x7fffu + ((u >> 16) & 1u)) >> 16;  // round-to-nearest-even
  return (u16)r;
}

// ---------------------------------------------------------------------------
// Tiled fp32 GEMM: C = op(A[M,K]) @ B[K,N] + bias, optional relu in/out,
// optional bf16 output. 64x64 tile, BK=16, 256 threads, 4x4 acc/thread.
// ---------------------------------------------------------------------------
template <int RELU_IN, int RELU_OUT, int OUT_BF16>
__global__ __launch_bounds__(256) void gemm_bias(
    const float* __restrict__ A, const float* __restrict__ B,
    const float* __restrict__ bias, void* __restrict__ Cout,
    int M, int N, int K) {
  __shared__ float As[16][64];
  __shared__ float Bs[16][64];

  const int tid = threadIdx.x;
  const int tx = tid & 15;
  const int ty = tid >> 4;
  const int bm = blockIdx.x * 64;
  const int bn = blockIdx.y * 64;

  float acc[4][4] = {};

  const int e = tid * 4;
  const int ar = e >> 4;
  const int ak = e & 15;
  const int bk = e >> 6;
  const int bn4 = e & 63;

  for (int k0 = 0; k0 < K; k0 += 16) {
    {
      float4 v = make_float4(0.f, 0.f, 0.f, 0.f);
      const int grow = bm + ar;
      if (grow < M)
        v = *reinterpret_cast<const float4*>(&A[(size_t)grow * K + k0 + ak]);
      if (RELU_IN) {
        v.x = fmaxf(v.x, 0.f); v.y = fmaxf(v.y, 0.f);
        v.z = fmaxf(v.z, 0.f); v.w = fmaxf(v.w, 0.f);
      }
      As[ak + 0][ar] = v.x;
      As[ak + 1][ar] = v.y;
      As[ak + 2][ar] = v.z;
      As[ak + 3][ar] = v.w;
    }
    {
      float4 v = *reinterpret_cast<const float4*>(
          &B[(size_t)(k0 + bk) * N + bn + bn4]);
      *reinterpret_cast<float4*>(&Bs[bk][bn4]) = v;
    }
    __syncthreads();

#pragma unroll
    for (int k = 0; k < 16; ++k) {
      float4 a = *reinterpret_cast<const float4*>(&As[k][ty * 4]);
      float4 b = *reinterpret_cast<const float4*>(&Bs[k][tx * 4]);
      const float av[4] = {a.x, a.y, a.z, a.w};
      const float bv[4] = {b.x, b.y, b.z, b.w};
#pragma unroll
      for (int i = 0; i < 4; ++i)
#pragma unroll
        for (int j = 0; j < 4; ++j) acc[i][j] += av[i] * bv[j];
    }
    __syncthreads();
  }

  const int cn = bn + tx * 4;
  float4 bv = *reinterpret_cast<const float4*>(&bias[cn]);
#pragma unroll
  for (int i = 0; i < 4; ++i) {
    const int row = bm + ty * 4 + i;
    if (row >= M) continue;
    float o[4];
    o[0] = acc[i][0] + bv.x;
    o[1] = acc[i][1] + bv.y;
    o[2] = acc[i][2] + bv.z;
    o[3] = acc[i][3] + bv.w;
    if (RELU_OUT) {
#pragma unroll
      for (int j = 0; j < 4; ++j) o[j] = fmaxf(o[j], 0.f);
    }
    if (OUT_BF16) {
      ushort4 p;
      p.x = f2bf(o[0]); p.y = f2bf(o[1]); p.z = f2bf(o[2]); p.w = f2bf(o[3]);
      *reinterpret_cast<ushort4*>(
          (u16*)Cout + (size_t)row * N + cn) = p;
    } else {
      float4 p = make_float4(o[0], o[1], o[2], o[3]);
      *reinterpret_cast<float4*>((float*)Cout + (size_t)row * N + cn) = p;
    }
  }
}

// ---------------------------------------------------------------------------
// CSR build: histogram -> single-block exclusive scan -> scatter
// ---------------------------------------------------------------------------
__global__ __launch_bounds__(256) void edge_hist(
    const int* __restrict__ rows, int* __restrict__ cnt, int nE) {
  int i = blockIdx.x * 256 + threadIdx.x;
  if (i < nE) atomicAdd(&cnt[rows[i]], 1);
}

// Exclusive scan of cnt[0..NN-1] -> ptr[0..NN]; also re-init cnt as cursor.
__global__ __launch_bounds__(1024) void scan_rowptr(
    int* __restrict__ cnt, int* __restrict__ ptr) {
  __shared__ int lds[1024];
  __shared__ int carry;
  if (threadIdx.x == 0) carry = 0;
  __syncthreads();
  for (int base = 0; base < NN; base += 1024) {
    const int i = base + threadIdx.x;
    const int v = (i < NN) ? cnt[i] : 0;
    lds[threadIdx.x] = v;
    __syncthreads();
#pragma unroll
    for (int off = 1; off < 1024; off <<= 1) {
      int t = (threadIdx.x >= off) ? lds[threadIdx.x - off] : 0;
      __syncthreads();
      lds[threadIdx.x] += t;
      __syncthreads();
    }
    const int excl = lds[threadIdx.x] - v;
    const int c = carry;
    if (i < NN) {
      ptr[i] = c + excl;
      cnt[i] = c + excl;  // cursor = row start
    }
    __syncthreads();
    if (threadIdx.x == 0) carry = c + lds[1023];
    __syncthreads();
  }
  if (threadIdx.x == 0) ptr[NN] = carry;
}

__global__ __launch_bounds__(256) void edge_scatter(
    const int* __restrict__ rows, const int* __restrict__ cols,
    const float* __restrict__ vals, int* __restrict__ cursor,
    int* __restrict__ ecol, float* __restrict__ eval, int nE) {
  int i = blockIdx.x * 256 + threadIdx.x;
  if (i >= nE) return;
  int pos = atomicAdd(&cursor[rows[i]], 1);
  ecol[pos] = cols[i];
  eval[pos] = vals[i];
}

// ---------------------------------------------------------------------------
// CSR SpMM width 256, bf16 input, fp32 out. One wave per row, lane = 4 cols.
// ---------------------------------------------------------------------------
__global__ __launch_bounds__(256) void spmm256_csr(
    const int* __restrict__ ptr, const int* __restrict__ ecol,
    const float* __restrict__ eval, const u16* __restrict__ Zb,
    float* __restrict__ Y) {
  const int wid = (int)((blockIdx.x * (size_t)blockDim.x + threadIdx.x) >> 6);
  const int lane = threadIdx.x & 63;
  if (wid >= NN) return;
  const int s = ptr[wid];
  const int e = ptr[wid + 1];
  float a0 = 0.f, a1 = 0.f, a2 = 0.f, a3 = 0.f;
  int j = s;
  for (; j + 1 < e; j += 2) {
    const int c0 = ecol[j], c1 = ecol[j + 1];
    const float v0 = eval[j], v1 = eval[j + 1];
    ushort4 u0 = reinterpret_cast<const ushort4*>(Zb + (size_t)c0 * 256)[lane];
    ushort4 u1 = reinterpret_cast<const ushort4*>(Zb + (size_t)c1 * 256)[lane];
    a0 += v0 * bf2f(u0.x) + v1 * bf2f(u1.x);
    a1 += v0 * bf2f(u0.y) + v1 * bf2f(u1.y);
    a2 += v0 * bf2f(u0.z) + v1 * bf2f(u1.z);
    a3 += v0 * bf2f(u0.w) + v1 * bf2f(u1.w);
  }
  if (j < e) {
    const int c0 = ecol[j];
    const float v0 = eval[j];
    ushort4 u0 = reinterpret_cast<const ushort4*>(Zb + (size_t)c0 * 256)[lane];
    a0 += v0 * bf2f(u0.x);
    a1 += v0 * bf2f(u0.y);
    a2 += v0 * bf2f(u0.z);
    a3 += v0 * bf2f(u0.w);
  }
  float4 o = make_float4(a0, a1, a2, a3);
  reinterpret_cast<float4*>(Y + (size_t)wid * 256)[lane] = o;
}

// ---------------------------------------------------------------------------
// CSR SpMM width 64, bf16 input, fp32 out. One wave per row, lane = 1 col.
// ---------------------------------------------------------------------------
__global__ __launch_bounds__(256) void spmm64_csr(
    const int* __restrict__ ptr, const int* __restrict__ ecol,
    const float* __restrict__ eval, const u16* __restrict__ Zb,
    float* __restrict__ Y) {
  const int wid = (int)((blockIdx.x * (size_t)blockDim.x + threadIdx.x) >> 6);
  const int lane = threadIdx.x & 63;
  if (wid >= NN) return;
  const int s = ptr[wid];
  const int e = ptr[wid + 1];
  float acc = 0.f;
  int j = s;
  for (; j + 1 < e; j += 2) {
    const int c0 = ecol[j], c1 = ecol[j + 1];
    const float v0 = eval[j], v1 = eval[j + 1];
    const u16 u0 = Zb[(size_t)c0 * 64 + lane];
    const u16 u1 = Zb[(size_t)c1 * 64 + lane];
    acc += v0 * bf2f(u0) + v1 * bf2f(u1);
  }
  if (j < e) {
    acc += eval[j] * bf2f(Zb[(size_t)ecol[j] * 64 + lane]);
  }
  Y[(size_t)wid * 64 + lane] = acc;
}

extern "C" void kernel_launch(void* const* d_in, const int* in_sizes, int n_in,
                              void* d_out, int out_size, void* d_ws,
                              size_t ws_size, hipStream_t stream) {
  const float* x_a  = (const float*)d_in[0];
  const float* x_b  = (const float*)d_in[1];
  const int*   rows = (const int*)d_in[2];
  const int*   cols = (const int*)d_in[3];
  const float* vals = (const float*)d_in[4];
  const float* W1a  = (const float*)d_in[5];
  const float* b1a  = (const float*)d_in[6];
  const float* W1b  = (const float*)d_in[7];
  const float* b1b  = (const float*)d_in[8];
  const float* Wf   = (const float*)d_in[9];
  const float* bf   = (const float*)d_in[10];
  const float* W2   = (const float*)d_in[11];
  const float* b2   = (const float*)d_in[12];
  float* out = (float*)d_out;

  // workspace layout (~193 MB)
  char* p = (char*)d_ws;
  float* h   = (float*)p;                 p += (size_t)NN * NHID * 4;  // 102.4MB (h, then s1)
  u16*  zb   = (u16*)p;                   p += (size_t)NN * NHID * 2;  // 51.2MB
  u16*  z2b  = (u16*)p;                   p += (size_t)NN * NOUT * 2;  // 12.8MB
  int*  ecol = (int*)p;                   p += (size_t)NE * 4;         // 12.8MB
  float* eval = (float*)p;                p += (size_t)NE * 4;         // 12.8MB
  int*  rptr = (int*)p;                   p += (size_t)(NN + 1) * 4;
  int*  cur  = (int*)p;                   p += (size_t)NN * 4;

  // --- CSR build (independent of GEMMs) ---
  hipMemsetAsync(cur, 0, (size_t)NN * 4, stream);
  edge_hist<<<(NE + 255) / 256, 256, 0, stream>>>(rows, cur, NE);
  scan_rowptr<<<1, 1024, 0, stream>>>(cur, rptr);
  edge_scatter<<<(NE + 255) / 256, 256, 0, stream>>>(rows, cols, vals, cur,
                                                     ecol, eval, NE);

  // --- dense pipeline ---
  // h_a = relu(x_a @ W1a + b1a); h_b = relu(x_b @ W1b + b1b)
  gemm_bias<0, 1, 0><<<dim3((NA + 63) / 64, NHID / 64), 256, 0, stream>>>(
      x_a, W1a, b1a, h, NA, NHID, 256);
  gemm_bias<0, 1, 0><<<dim3((NB + 63) / 64, NHID / 64), 256, 0, stream>>>(
      x_b, W1b, b1b, h + (size_t)NA * NHID, NB, NHID, 128);
  // zb = bf16(h @ Wf + bf)
  gemm_bias<0, 0, 1><<<dim3((NN + 63) / 64, NHID / 64), 256, 0, stream>>>(
      h, Wf, bf, zb, NN, NHID, NHID);
  // s1 = spmm(zb)  (fp32, overwrites h)
  spmm256_csr<<<(NN * 64 + 255) / 256, 256, 0, stream>>>(rptr, ecol, eval, zb,
                                                         h);
  // z2b = bf16(relu(s1) @ W2 + b2)
  gemm_bias<1, 0, 1><<<dim3((NN + 63) / 64, NOUT / 64), 256, 0, stream>>>(
      h, W2, b2, z2b, NN, NOUT, NHID);
  // out = spmm(z2b)
  spmm64_csr<<<(NN * 64 + 255) / 256, 256, 0, stream>>>(rptr, ecol, eval, z2b,
                                                        out);
}

// Round 3
// 805.956 us; speedup vs baseline: 14.4621x; 1.6015x over previous
//
#include <hip/hip_runtime.h>

#define NN 100000
#define NE 3200000
#define NA 60000
#define NB 40000
#define NHID 256
#define NOUT 64
#define NBLK 98  // ceil(NN/1024)

typedef unsigned short u16;
typedef unsigned int u32;
typedef __attribute__((ext_vector_type(8))) short short8;
typedef __attribute__((ext_vector_type(4))) float f32x4;

__device__ __forceinline__ float bf2f(u16 u) {
  return __uint_as_float(((u32)u) << 16);
}
__device__ __forceinline__ u16 f2bf(float f) {
  u32 u = __float_as_uint(f);
  u32 r = (u + 0x7fffu + ((u >> 16) & 1u)) >> 16;  // RNE
  return (u16)r;
}

// async global->LDS, 16B per lane; LDS dest is wave-uniform base (+lane*16 HW)
__device__ __forceinline__ void gload_lds16(const void* gsrc, void* ldst) {
  __builtin_amdgcn_global_load_lds(
      (const __attribute__((address_space(1))) void*)gsrc,
      (__attribute__((address_space(3))) void*)ldst, 16, 0, 0);
}

// ---------------------------------------------------------------------------
// bf16 MFMA GEMM: C[M,N]bf16 = A[M,K]bf16 @ Bt[N,K]bf16^T + bias, opt relu.
// BM=128. BN=128: 4 waves 2x2, wave tile 64x64 (4x4 frags).
//         BN=64 : 4 waves 4x1, wave tile 32x64 (2x4 frags).
// BK=32 per step. LDS chunk-XOR swizzle: 16B chunk c stored at c^((row>>1)&3)
// (applied on global source; ds_read applies same XOR) -> 2-way max conflict.
// ---------------------------------------------------------------------------
template <int BN, int RELU_OUT>
__global__ __launch_bounds__(256) void gemm_mfma(
    const u16* __restrict__ A, const u16* __restrict__ Bt,
    const float* __restrict__ bias, u16* __restrict__ C,
    int M, int N, int K) {
  constexpr int BM = 128;
  constexpr int FI = (BN == 128) ? 4 : 2;
  constexpr int WROWS = FI * 16;  // 64 or 32
  __shared__ __align__(16) u16 As[BM * 32];
  __shared__ __align__(16) u16 Bs[BN * 32];

  const int tid = threadIdx.x;
  const int w = tid >> 6;
  const int lane = tid & 63;
  const int bm = blockIdx.x * BM;
  const int bn = blockIdx.y * BN;
  const int wr = (BN == 128) ? (w >> 1) : w;
  const int wc = (BN == 128) ? (w & 1) : 0;

  f32x4 acc[FI][4];
#pragma unroll
  for (int i = 0; i < FI; ++i)
#pragma unroll
    for (int j = 0; j < 4; ++j) acc[i][j] = (f32x4)0.f;

  for (int k0 = 0; k0 < K; k0 += 32) {
    // --- stage A tile [128][32] : 8 x 1KB wave-instructions ---
#pragma unroll
    for (int s = 0; s < 2; ++s) {
      const int inst = w * 2 + s;
      const int row = inst * 16 + (lane >> 2);
      int rg = bm + row;
      if (rg > M - 1) rg = M - 1;
      const int c = (lane & 3) ^ ((row >> 1) & 3);
      gload_lds16(A + (size_t)rg * K + k0 + c * 8, &As[inst * 512]);
    }
    // --- stage B tile [BN][32] ---
    if (BN == 128) {
#pragma unroll
      for (int s = 0; s < 2; ++s) {
        const int inst = w * 2 + s;
        const int row = inst * 16 + (lane >> 2);
        const int c = (lane & 3) ^ ((row >> 1) & 3);
        gload_lds16(Bt + (size_t)(bn + row) * K + k0 + c * 8,
                    &Bs[inst * 512]);
      }
    } else {
      const int inst = w;
      const int row = inst * 16 + (lane >> 2);
      const int c = (lane & 3) ^ ((row >> 1) & 3);
      gload_lds16(Bt + (size_t)(bn + row) * K + k0 + c * 8, &Bs[inst * 512]);
    }
    __syncthreads();

    // --- fragments + MFMA ---
    const int kc = lane >> 4;
    short8 af[FI], bfr[4];
#pragma unroll
    for (int i = 0; i < FI; ++i) {
      const int row = wr * WROWS + i * 16 + (lane & 15);
      const int ch = kc ^ ((row >> 1) & 3);
      af[i] = *reinterpret_cast<const short8*>(&As[row * 32 + ch * 8]);
    }
#pragma unroll
    for (int j = 0; j < 4; ++j) {
      const int row = wc * 64 + j * 16 + (lane & 15);
      const int ch = kc ^ ((row >> 1) & 3);
      bfr[j] = *reinterpret_cast<const short8*>(&Bs[row * 32 + ch * 8]);
    }
#pragma unroll
    for (int i = 0; i < FI; ++i)
#pragma unroll
      for (int j = 0; j < 4; ++j)
        acc[i][j] = __builtin_amdgcn_mfma_f32_16x16x32_bf16(af[i], bfr[j],
                                                            acc[i][j], 0, 0, 0);
    __syncthreads();
  }

  // --- epilogue: C/D layout col=lane&15, row=(lane>>4)*4+reg ---
#pragma unroll
  for (int i = 0; i < FI; ++i) {
#pragma unroll
    for (int j = 0; j < 4; ++j) {
      const int col = bn + wc * 64 + j * 16 + (lane & 15);
      const float bv = bias[col];
#pragma unroll
      for (int r = 0; r < 4; ++r) {
        const int row = bm + wr * WROWS + i * 16 + (lane >> 4) * 4 + r;
        if (row < M) {
          float o = acc[i][j][r] + bv;
          if (RELU_OUT) o = fmaxf(o, 0.f);
          C[(size_t)row * N + col] = f2bf(o);
        }
      }
    }
  }
}

// ---------------------------------------------------------------------------
// conversions
// ---------------------------------------------------------------------------
__global__ __launch_bounds__(256) void cvt_bf16(const float4* __restrict__ in,
                                                ushort4* __restrict__ out,
                                                int n4) {
  const int i = blockIdx.x * 256 + threadIdx.x;
  if (i >= n4) return;
  const float4 v = in[i];
  ushort4 o;
  o.x = f2bf(v.x); o.y = f2bf(v.y); o.z = f2bf(v.z); o.w = f2bf(v.w);
  out[i] = o;
}

// W [K][N] f32 -> Wt [N][K] bf16
__global__ __launch_bounds__(256) void wt_transpose(const float* __restrict__ W,
                                                    u16* __restrict__ Wt,
                                                    int K, int N) {
  const int i = blockIdx.x * 256 + threadIdx.x;
  if (i >= N * K) return;
  const int n = i / K;
  const int k = i - n * K;
  Wt[i] = f2bf(W[(size_t)k * N + n]);
}

// ---------------------------------------------------------------------------
// CSR build
// ---------------------------------------------------------------------------
__global__ __launch_bounds__(256) void edge_hist(const int* __restrict__ rows,
                                                 int* __restrict__ cnt,
                                                 int nE) {
  const int i = blockIdx.x * 256 + threadIdx.x;
  if (i < nE) atomicAdd(&cnt[rows[i]], 1);
}

// per-block exclusive scan (1024 elems/block) -> rptr, block totals -> btot
__global__ __launch_bounds__(1024) void scan1(const int* __restrict__ cnt,
                                              int* __restrict__ rptr,
                                              int* __restrict__ btot) {
  __shared__ int lds[1024];
  const int t = threadIdx.x;
  const int i = blockIdx.x * 1024 + t;
  const int v = (i < NN) ? cnt[i] : 0;
  lds[t] = v;
  __syncthreads();
#pragma unroll
  for (int off = 1; off < 1024; off <<= 1) {
    const int x = (t >= off) ? lds[t - off] : 0;
    __syncthreads();
    lds[t] += x;
    __syncthreads();
  }
  if (i < NN) rptr[i] = lds[t] - v;
  if (t == 1023) btot[blockIdx.x] = lds[1023];
}

// exclusive scan of NBLK block totals
__global__ __launch_bounds__(128) void scan2(int* __restrict__ btot) {
  __shared__ int lds[128];
  const int t = threadIdx.x;
  const int v = (t < NBLK) ? btot[t] : 0;
  lds[t] = v;
  __syncthreads();
#pragma unroll
  for (int off = 1; off < 128; off <<= 1) {
    const int x = (t >= off) ? lds[t - off] : 0;
    __syncthreads();
    lds[t] += x;
    __syncthreads();
  }
  if (t < NBLK) btot[t] = lds[t] - v;
}

// add block offsets; init cursor; set rptr[NN]
__global__ __launch_bounds__(1024) void scan3(int* __restrict__ rptr,
                                              const int* __restrict__ btot,
                                              int* __restrict__ cur) {
  const int t = threadIdx.x;
  const int i = blockIdx.x * 1024 + t;
  if (i < NN) {
    const int p = rptr[i] + btot[blockIdx.x];
    rptr[i] = p;
    cur[i] = p;
  }
  if (i == 0) rptr[NN] = NE;
}

__global__ __launch_bounds__(256) void edge_scatter(
    const int* __restrict__ rows, const int* __restrict__ cols,
    const float* __restrict__ vals, int* __restrict__ cur,
    int2* __restrict__ edges, int nE) {
  const int i = blockIdx.x * 256 + threadIdx.x;
  if (i >= nE) return;
  const int pos = atomicAdd(&cur[rows[i]], 1);
  edges[pos] = make_int2(cols[i], __float_as_int(vals[i]));
}

// ---------------------------------------------------------------------------
// CSR SpMM width 256 (bf16 in, relu+bf16 out). One wave/row, lane = 4 cols.
// ---------------------------------------------------------------------------
__global__ __launch_bounds__(256) void spmm256_csr(
    const int* __restrict__ ptr, const int2* __restrict__ edges,
    const u16* __restrict__ Zb, u16* __restrict__ Yb) {
  const int wid = (int)((blockIdx.x * (size_t)256 + threadIdx.x) >> 6);
  const int lane = threadIdx.x & 63;
  if (wid >= NN) return;
  const int s = ptr[wid], e = ptr[wid + 1];
  float a0 = 0.f, a1 = 0.f, a2 = 0.f, a3 = 0.f;
  int j = s;
  for (; j + 3 < e; j += 4) {
    const int2 e0 = edges[j], e1 = edges[j + 1];
    const int2 e2 = edges[j + 2], e3 = edges[j + 3];
    const ushort4 u0 =
        reinterpret_cast<const ushort4*>(Zb + (size_t)e0.x * 256)[lane];
    const ushort4 u1 =
        reinterpret_cast<const ushort4*>(Zb + (size_t)e1.x * 256)[lane];
    const ushort4 u2 =
        reinterpret_cast<const ushort4*>(Zb + (size_t)e2.x * 256)[lane];
    const ushort4 u3 =
        reinterpret_cast<const ushort4*>(Zb + (size_t)e3.x * 256)[lane];
    const float v0 = __int_as_float(e0.y), v1 = __int_as_float(e1.y);
    const float v2 = __int_as_float(e2.y), v3 = __int_as_float(e3.y);
    a0 += v0 * bf2f(u0.x) + v1 * bf2f(u1.x) + v2 * bf2f(u2.x) + v3 * bf2f(u3.x);
    a1 += v0 * bf2f(u0.y) + v1 * bf2f(u1.y) + v2 * bf2f(u2.y) + v3 * bf2f(u3.y);
    a2 += v0 * bf2f(u0.z) + v1 * bf2f(u1.z) + v2 * bf2f(u2.z) + v3 * bf2f(u3.z);
    a3 += v0 * bf2f(u0.w) + v1 * bf2f(u1.w) + v2 * bf2f(u2.w) + v3 * bf2f(u3.w);
  }
  for (; j < e; ++j) {
    const int2 e0 = edges[j];
    const ushort4 u0 =
        reinterpret_cast<const ushort4*>(Zb + (size_t)e0.x * 256)[lane];
    const float v0 = __int_as_float(e0.y);
    a0 += v0 * bf2f(u0.x);
    a1 += v0 * bf2f(u0.y);
    a2 += v0 * bf2f(u0.z);
    a3 += v0 * bf2f(u0.w);
  }
  ushort4 o;  // fused relu + bf16
  o.x = f2bf(fmaxf(a0, 0.f));
  o.y = f2bf(fmaxf(a1, 0.f));
  o.z = f2bf(fmaxf(a2, 0.f));
  o.w = f2bf(fmaxf(a3, 0.f));
  reinterpret_cast<ushort4*>(Yb + (size_t)wid * 256)[lane] = o;
}

// ---------------------------------------------------------------------------
// CSR SpMM width 64 (bf16 in, fp32 out). One wave/row, lane = 1 col.
// ---------------------------------------------------------------------------
__global__ __launch_bounds__(256) void spmm64_csr(
    const int* __restrict__ ptr, const int2* __restrict__ edges,
    const u16* __restrict__ Zb, float* __restrict__ Y) {
  const int wid = (int)((blockIdx.x * (size_t)256 + threadIdx.x) >> 6);
  const int lane = threadIdx.x & 63;
  if (wid >= NN) return;
  const int s = ptr[wid], e = ptr[wid + 1];
  float acc = 0.f;
  int j = s;
  for (; j + 3 < e; j += 4) {
    const int2 e0 = edges[j], e1 = edges[j + 1];
    const int2 e2 = edges[j + 2], e3 = edges[j + 3];
    const u16 u0 = Zb[(size_t)e0.x * 64 + lane];
    const u16 u1 = Zb[(size_t)e1.x * 64 + lane];
    const u16 u2 = Zb[(size_t)e2.x * 64 + lane];
    const u16 u3 = Zb[(size_t)e3.x * 64 + lane];
    acc += __int_as_float(e0.y) * bf2f(u0) + __int_as_float(e1.y) * bf2f(u1) +
           __int_as_float(e2.y) * bf2f(u2) + __int_as_float(e3.y) * bf2f(u3);
  }
  for (; j < e; ++j)
    acc += __int_as_float(edges[j].y) * bf2f(Zb[(size_t)edges[j].x * 64 + lane]);
  Y[(size_t)wid * 64 + lane] = acc;
}

extern "C" void kernel_launch(void* const* d_in, const int* in_sizes, int n_in,
                              void* d_out, int out_size, void* d_ws,
                              size_t ws_size, hipStream_t stream) {
  const float* x_a  = (const float*)d_in[0];
  const float* x_b  = (const float*)d_in[1];
  const int*   rows = (const int*)d_in[2];
  const int*   cols = (const int*)d_in[3];
  const float* vals = (const float*)d_in[4];
  const float* W1a  = (const float*)d_in[5];
  const float* b1a  = (const float*)d_in[6];
  const float* W1b  = (const float*)d_in[7];
  const float* b1b  = (const float*)d_in[8];
  const float* Wf   = (const float*)d_in[9];
  const float* bf   = (const float*)d_in[10];
  const float* W2   = (const float*)d_in[11];
  const float* b2   = (const float*)d_in[12];
  float* out = (float*)d_out;

  // workspace (~183 MB)
  char* p = (char*)d_ws;
  u16* h    = (u16*)p;  p += (size_t)NN * NHID * 2;   // 51.2MB (h, later s1b)
  u16* zb   = (u16*)p;  p += (size_t)NN * NHID * 2;   // 51.2MB
  u16* z2b  = (u16*)p;  p += (size_t)NN * NOUT * 2;   // 12.8MB
  u16* xab  = (u16*)p;  p += (size_t)NA * 256 * 2;    // 30.7MB
  u16* xbb  = (u16*)p;  p += (size_t)NB * 128 * 2;    // 10.2MB
  u16* W1at = (u16*)p;  p += 256 * 256 * 2;
  u16* W1bt = (u16*)p;  p += 256 * 128 * 2;
  u16* Wft  = (u16*)p;  p += 256 * 256 * 2;
  u16* W2t  = (u16*)p;  p += 64 * 256 * 2;
  int2* edges = (int2*)p; p += (size_t)NE * 8;        // 25.6MB
  int* rptr = (int*)p;  p += (size_t)(NN + 2) * 4;
  int* cur  = (int*)p;  p += (size_t)NN * 4;
  int* btot = (int*)p;  p += 512;
  u16* s1b = h;  // h dead after gemm3; reuse for relu(spmm(zb)) in bf16

  // --- CSR build ---
  hipMemsetAsync(cur, 0, (size_t)NN * 4, stream);
  edge_hist<<<(NE + 255) / 256, 256, 0, stream>>>(rows, cur, NE);
  scan1<<<NBLK, 1024, 0, stream>>>(cur, rptr, btot);
  scan2<<<1, 128, 0, stream>>>(btot);
  scan3<<<NBLK, 1024, 0, stream>>>(rptr, btot, cur);
  edge_scatter<<<(NE + 255) / 256, 256, 0, stream>>>(rows, cols, vals, cur,
                                                     edges, NE);

  // --- input / weight conversion ---
  cvt_bf16<<<(NA * 256 / 4 + 255) / 256, 256, 0, stream>>>(
      (const float4*)x_a, (ushort4*)xab, NA * 256 / 4);
  cvt_bf16<<<(NB * 128 / 4 + 255) / 256, 256, 0, stream>>>(
      (const float4*)x_b, (ushort4*)xbb, NB * 128 / 4);
  wt_transpose<<<(256 * 256 + 255) / 256, 256, 0, stream>>>(W1a, W1at, 256, 256);
  wt_transpose<<<(256 * 128 + 255) / 256, 256, 0, stream>>>(W1b, W1bt, 128, 256);
  wt_transpose<<<(256 * 256 + 255) / 256, 256, 0, stream>>>(Wf, Wft, 256, 256);
  wt_transpose<<<(64 * 256 + 255) / 256, 256, 0, stream>>>(W2, W2t, 256, 64);

  // --- dense pipeline (all bf16 MFMA) ---
  gemm_mfma<128, 1><<<dim3((NA + 127) / 128, 2), 256, 0, stream>>>(
      xab, W1at, b1a, h, NA, NHID, 256);
  gemm_mfma<128, 1><<<dim3((NB + 127) / 128, 2), 256, 0, stream>>>(
      xbb, W1bt, b1b, h + (size_t)NA * NHID, NB, NHID, 128);
  gemm_mfma<128, 0><<<dim3((NN + 127) / 128, 2), 256, 0, stream>>>(
      h, Wft, bf, zb, NN, NHID, 256);
  // s1b = bf16(relu(spmm(zb)))  (reuses h)
  spmm256_csr<<<(NN * 64 + 255) / 256, 256, 0, stream>>>(rptr, edges, zb, s1b);
  gemm_mfma<64, 0><<<dim3((NN + 127) / 128, 1), 256, 0, stream>>>(
      s1b, W2t, b2, z2b, NN, NOUT, 256);
  // out = spmm(z2b)
  spmm64_csr<<<(NN * 64 + 255) / 256, 256, 0, stream>>>(rptr, edges, z2b, out);
}